// Round 5
// baseline (196.645 us; speedup 1.0000x reference)
//
#include <hip/hip_runtime.h>
#include <hip/hip_fp16.h>

// Fused Sinkhorn OT. n=64, in_size=1024, in_dim=128, heads=4, out_size=64.
// Single kernel, 256 blocks x 1024 threads (1 block/CU):
//   P1: K-GEMM (fp32 pk-fma, W^T staged LDS) -> EK=exp(K) in regs (8x8/thread)
//   P2: multiplicative Sinkhorn, ONE barrier/iter. Model (R12): P2 is
//       VALU-ISSUE-bound (4 waves/SIMD share the issue port; slowest blocks
//       sit at the 100-iter cap), so the lever is instructions/iter.
//       (A) row sums: in-thread pk-dot + xor1/2/4 quad-DPP (unchanged).
//       (B) col partials REPLACED by MFMA: per wave, D = E^T(64x64) . u via
//           8x mfma_f32_16x16x32_f16. A-frags = E^T in f16, built ONCE after
//           P1 via LDS-transposed staging (layout idiom identical to P3's
//           working A-frag: row=lane&15, k=8*(lane>>4)+j). B = u in col 0:
//           4 cvt_pk + 8 ds_bpermute. Lanes&15==0 store D as 4x b128 into cw.
//           ~85 VALU instrs/iter -> ~35 + 8 MFMA (separate pipe).
//           f16-E is a FIXED perturbation (residual of perturbed matrix still
//           -> 0, exit fires); f16-u noise averages over 1024 rows (~2e-5
//           residual floor < 1e-4 tol). E2 f32 stays master for T.
//       (C) cross-wave tree-sum + ballot exit (tol 1e-4, skip it<8) + 8x
//           ds_bpermute ev redistribution (unchanged). Cap 100.
//   P3: out = T^T x on MFMA f32_16x16x32_f16, R7 structure: double-buffered
//       128-row chunks, T pre-packed to f16 regs (hhT), next chunk's x loads
//       issued before the MFMA block (no regs live across barriers -> no
//       spills).

typedef _Float16 half8 __attribute__((ext_vector_type(8)));
typedef float f32x4 __attribute__((ext_vector_type(4)));

__device__ __forceinline__ float2 pkfma(float2 a, float2 b, float2 c) {
  return make_float2(fmaf(a.x, b.x, c.x), fmaf(a.y, b.y, c.y));
}

template <int CTRL>
__device__ __forceinline__ float dpp_add(float v) {
  return v + __int_as_float(__builtin_amdgcn_update_dpp(
                 0, __float_as_int(v), CTRL, 0xf, 0xf, true));
}

// XCD-aware batch map: 4 heads of one nb + 8 nb per XCD (4 MB x-slice = L2).
__device__ __forceinline__ void batch_map(int bb, int& nb, int& m) {
  int k = bb >> 3;
  nb = 8 * (bb & 7) + (k >> 2);
  m = k & 3;
}

__global__ __launch_bounds__(1024, 4) void ot_fused_kernel(
    const float* __restrict__ x, const float* __restrict__ w,
    float* __restrict__ out) {
  int nb, m;
  batch_map(blockIdx.x, nb, m);
  const int t = threadIdx.x;
  const int gi = t >> 3;  // rows 8*gi..8*gi+7
  const int gj = t & 7;   // cols 8*gj..8*gj+7
  const int lane = t & 63;
  const int wvw = t >> 6;   // wave 0..15
  const int qi = lane >> 3; // row-oct within wave (local rows 8*qi..+7)
  const int ml = lane & 15;
  const int kq = lane >> 4;

  __shared__ union {
    float wt[128][68];        // P1 staging
    __half tsc[8 * 64 * 72];  // P2 E^T f16 staging (8 wave-slots, once)
    struct {
      __half Xh[2][128 * 128];  // P3 x chunks, f16, [d][i-local] swizzled
      __half To[2][64 * 128];   // P3 T chunks, f16, [o][i-local] swizzled
    } p3;                       // 96 KB
  } u_;
  __shared__ float cw[2][16][68];  // P2 col partials, parity-buffered

  // ---- P1a: stage W^T ----
  const float* wm = w + (size_t)m * 64 * 128;
  for (int e = t; e < 64 * 128; e += 1024) {
    int j = e >> 7, d = e & 127;
    u_.wt[d][j] = wm[e];
  }
  __syncthreads();

  // ---- P1b: K tile (8x8/thread), EK = exp(K) ----
  float2 E2[8][4];
  #pragma unroll
  for (int r = 0; r < 8; ++r)
    #pragma unroll
    for (int c = 0; c < 4; ++c) E2[r][c] = make_float2(0.f, 0.f);

  const float* xrow = x + (size_t)nb * 1024 * 128 + (size_t)gi * 8 * 128;
  for (int d = 0; d < 128; d += 4) {
    float2 wr[4][4];
    #pragma unroll
    for (int dd = 0; dd < 4; ++dd) {
      float4 a0 = *(const float4*)&u_.wt[d + dd][8 * gj];
      float4 a1 = *(const float4*)&u_.wt[d + dd][8 * gj + 4];
      wr[dd][0] = make_float2(a0.x, a0.y);
      wr[dd][1] = make_float2(a0.z, a0.w);
      wr[dd][2] = make_float2(a1.x, a1.y);
      wr[dd][3] = make_float2(a1.z, a1.w);
    }
    #pragma unroll
    for (int r = 0; r < 8; ++r) {
      float4 xv = *(const float4*)&xrow[r * 128 + d];
      float xs[4] = {xv.x, xv.y, xv.z, xv.w};
      #pragma unroll
      for (int dd = 0; dd < 4; ++dd)
        #pragma unroll
        for (int c = 0; c < 4; ++c)
          E2[r][c] = pkfma(make_float2(xs[dd], xs[dd]), wr[dd][c], E2[r][c]);
    }
  }
  #pragma unroll
  for (int r = 0; r < 8; ++r)
    #pragma unroll
    for (int c = 0; c < 4; ++c) {
      E2[r][c].x = __expf(E2[r][c].x);
      E2[r][c].y = __expf(E2[r][c].y);
    }
  __syncthreads();

  // ---- P2 pre: build E^T f16 A-fragments (once). Per wave: its 64x64
  //      E-block, stored TRANSPOSED in LDS ([colE][rowE], row stride 72
  //      halves = 144 B, b128-aligned), then 8x ds_read_b128 -> afr.
  //      Two phases of 8 waves (LDS scratch = 8 slots x 9216 B = 72 KB).
  half8 afr[4][2];  // [col-tile 16][K-tile 32]
  #pragma unroll
  for (int ph = 0; ph < 2; ++ph) {
    if ((wvw >> 3) == ph) {
      __half* tb = &u_.tsc[(wvw & 7) * 64 * 72];
      #pragma unroll
      for (int cc = 0; cc < 8; ++cc) {  // local col 8*gj+cc
        const int c = cc >> 1;
        __half2 hp[4];
        #pragma unroll
        for (int s = 0; s < 4; ++s) {
          float va = (cc & 1) ? E2[2 * s][c].y : E2[2 * s][c].x;
          float vb = (cc & 1) ? E2[2 * s + 1][c].y : E2[2 * s + 1][c].x;
          hp[s] = __float22half2_rn(make_float2(va, vb));
        }
        *(uint4*)&tb[(8 * gj + cc) * 72 + 8 * qi] = *(uint4*)hp;
      }
    }
    __syncthreads();
    if ((wvw >> 3) == ph) {
      const __half* tb = &u_.tsc[(wvw & 7) * 64 * 72];
      #pragma unroll
      for (int tt = 0; tt < 4; ++tt)
        #pragma unroll
        for (int kk = 0; kk < 2; ++kk)
          afr[tt][kk] =
              *(const half8*)&tb[(16 * tt + ml) * 72 + 32 * kk + 8 * kq];
    }
    __syncthreads();
  }

  // ---- P2: Sinkhorn, 1 barrier/iter ----
  // Scaling: ur = rcp(sum E*v) (true u / a). Fixed point preserved via
  // v = rcp(a*ss); T = diag(a*ur) E diag(v) applied in P3 prologue.
  float ur[8];
  float evj = 1.0f;    // v for column j==lane
  float evh = 0.0625f; // a*evj, residual scale (off critical path)
  const int bpa = 32 * gj;  // ds_bpermute byte base: source lane 8*gj
  float2 ep[4] = {make_float2(1.f, 1.f), make_float2(1.f, 1.f),
                  make_float2(1.f, 1.f), make_float2(1.f, 1.f)};
  for (int it = 0; it < 100; ++it) {
    const int pb = it & 1;
    // (A) row sums: in-thread pk-dot + xor1/2/4 quad-DPP over gj
    #pragma unroll
    for (int r = 0; r < 8; ++r) {
      float2 a = make_float2(0.f, 0.f);
      #pragma unroll
      for (int c = 0; c < 4; ++c) a = pkfma(E2[r][c], ep[c], a);
      float sr = a.x + a.y;
      sr = dpp_add<0xB1>(sr);
      sr = dpp_add<0x4E>(sr);
      sr = dpp_add<0x141>(sr);
      ur[r] = __builtin_amdgcn_rcpf(sr);
    }
    // (B) col partials via MFMA: D_t = (E^T)_t . u over this wave's 64 rows.
    //     u packed f16 into B col 0: pairs (ur[2p],ur[2p+1]) live at source
    //     lane 8*(4*kk+kq); bpermute pulls them into the B-frag lanes.
    {
      unsigned hu[4];
      #pragma unroll
      for (int p2 = 0; p2 < 4; ++p2) {
        __half2 hh =
            __float22half2_rn(make_float2(ur[2 * p2], ur[2 * p2 + 1]));
        hu[p2] = *(unsigned*)&hh;
      }
      half8 bf[2];
      #pragma unroll
      for (int kk = 0; kk < 2; ++kk) {
        union { unsigned u[4]; half8 h; } bw;
        #pragma unroll
        for (int p2 = 0; p2 < 4; ++p2)
          bw.u[p2] = (unsigned)__builtin_amdgcn_ds_bpermute(
              32 * kq + 128 * kk, (int)hu[p2]);
        bf[kk] = bw.h;
      }
      f32x4 Dv[4];
      #pragma unroll
      for (int tt = 0; tt < 4; ++tt) {
        Dv[tt] = f32x4{0.f, 0.f, 0.f, 0.f};
        Dv[tt] = __builtin_amdgcn_mfma_f32_16x16x32_f16(afr[tt][0], bf[0],
                                                        Dv[tt], 0, 0, 0);
        Dv[tt] = __builtin_amdgcn_mfma_f32_16x16x32_f16(afr[tt][1], bf[1],
                                                        Dv[tt], 0, 0, 0);
      }
      // D col 0 (== every col; B cols identical): rows = colE 16*tt+4*kq+reg.
      if (ml == 0) {
        #pragma unroll
        for (int tt = 0; tt < 4; ++tt)
          *(f32x4*)&cw[pb][wvw][16 * tt + 4 * kq] = Dv[tt];
      }
    }
    __syncthreads();
    // (C) every wave: tree-sum 16 partials for col=lane (identical data in
    //     all waves -> exit decision stays wave-uniform), ballot (skipped
    //     for it<8: residual provably >> tol there), redistribute via 8x
    //     ds_bpermute.
    float sv[16];
    #pragma unroll
    for (int p = 0; p < 16; ++p) sv[p] = cw[pb][p][lane];
    #pragma unroll
    for (int st = 8; st >= 1; st >>= 1)
      #pragma unroll
      for (int p = 0; p < st; ++p) sv[p] += sv[p + st];
    const float ss = sv[0];
    unsigned long long bad = ~0ULL;
    if (it >= 8) bad = __ballot(fabsf(fmaf(ss, evh, -1.0f)) > 1e-4f);
    evj = __builtin_amdgcn_rcpf(ss * 0.0625f);
    evh = 0.0625f * evj;
    int e[8];
    #pragma unroll
    for (int k = 0; k < 8; ++k)
      e[k] = __builtin_amdgcn_ds_bpermute(bpa + 4 * k, __float_as_int(evj));
    ep[0] = make_float2(__int_as_float(e[0]), __int_as_float(e[1]));
    ep[1] = make_float2(__int_as_float(e[2]), __int_as_float(e[3]));
    ep[2] = make_float2(__int_as_float(e[4]), __int_as_float(e[5]));
    ep[3] = make_float2(__int_as_float(e[6]), __int_as_float(e[7]));
    if (bad == 0ULL) break;
  }

  // ---- P3 prologue: scale T (a folded back in), pack to f16 regs hhT ----
  #pragma unroll
  for (int r = 0; r < 8; ++r) {
    const float us = ur[r] * 0.0625f;
    float2 uu = make_float2(us, us);
    #pragma unroll
    for (int c = 0; c < 4; ++c) {
      E2[r][c].x = E2[r][c].x * uu.x * ep[c].x;
      E2[r][c].y = E2[r][c].y * uu.y * ep[c].y;
    }
  }
  __half2 hhT[8][4];  // hhT[co][q] = (T[2q][co], T[2q+1][co])
  #pragma unroll
  for (int co = 0; co < 8; ++co)
    #pragma unroll
    for (int q = 0; q < 4; ++q) {
      float va = (co & 1) ? E2[2 * q][co >> 1].y : E2[2 * q][co >> 1].x;
      float vb =
          (co & 1) ? E2[2 * q + 1][co >> 1].y : E2[2 * q + 1][co >> 1].x;
      hhT[co][q] = __float22half2_rn(make_float2(va, vb));
    }

  // ---- P3: out = T^T x via MFMA, double-buffered 128-row chunks ----
  const int ig4 = t >> 5;    // i-quad group 0..31 (rows 4*ig4..+3 of chunk)
  const int dq = t & 31;     // d-quad
  const int o8w = ig4 >> 1;  // logical i-oct of this stager
  const int hw = ig4 & 1;    // half within oct
  const int ota = wvw & 3;
  const int dtb = wvw >> 2;
  const int oA = 16 * ota + ml;
  const int d0 = 32 * dtb + ml;
  const int d1 = d0 + 16;
  const int swA = oA & 15;
  const int swB0 = ((d0 >> 2) & 15) ^ ((d0 & 3) << 2);
  const int swB1 = ((d1 >> 2) & 15) ^ ((d1 & 3) << 2);

  f32x4 acc0 = {0.f, 0.f, 0.f, 0.f}, acc1 = {0.f, 0.f, 0.f, 0.f};
  const float* xb = x + (size_t)nb * 1024 * 128;

  auto stage_x = [&](int p, const float4* xv) {
    #pragma unroll
    for (int k = 0; k < 4; ++k) {
      const float* f0 = (const float*)&xv[0];
      const float* f1 = (const float*)&xv[1];
      const float* f2 = (const float*)&xv[2];
      const float* f3 = (const float*)&xv[3];
      __half2 hp[2];
      hp[0] = __float22half2_rn(make_float2(f0[k], f1[k]));
      hp[1] = __float22half2_rn(make_float2(f2[k], f3[k]));
      const int d = 4 * dq + k;
      const int pos = (o8w ^ (dq & 15) ^ (k << 2)) & 15;
      *(uint2*)&u_.p3.Xh[p][d * 128 + pos * 8 + hw * 4] = *(uint2*)hp;
    }
  };
  auto stage_T = [&](int c, int p) {
    if ((t >> 7) == c) {  // this thread's 8 rows live in chunk c
      const int g = gi & 15;
      #pragma unroll
      for (int co = 0; co < 8; ++co) {
        const int o = 8 * gj + co;
        const int pos = (g ^ (o & 15)) & 15;
        *(uint4*)&u_.p3.To[p][o * 128 + pos * 8] = *(const uint4*)&hhT[co][0];
      }
    }
  };

  // prologue: stage chunk 0 into buf 0
  {
    float4 xv[4];
    const float* xs = xb + (size_t)(4 * ig4) * 128 + 4 * dq;
    #pragma unroll
    for (int r = 0; r < 4; ++r) xv[r] = *(const float4*)(xs + r * 128);
    stage_x(0, xv);
    stage_T(0, 0);
  }
  __syncthreads();

  for (int c = 0; c < 8; ++c) {
    const int p = c & 1;
    float4 xv[4];
    if (c < 7) {  // issue next chunk's loads; complete under MFMA below
      const float* xs = xb + (size_t)(128 * (c + 1) + 4 * ig4) * 128 + 4 * dq;
      #pragma unroll
      for (int r = 0; r < 4; ++r) xv[r] = *(const float4*)(xs + r * 128);
    }
    // MFMA on current buffer: 4 K-steps of 32
    #pragma unroll
    for (int s = 0; s < 4; ++s) {
      const int gk = 4 * s + kq;
      half8 af =
          *(const half8*)&u_.p3.To[p][oA * 128 + ((gk ^ swA) & 15) * 8];
      half8 b0 =
          *(const half8*)&u_.p3.Xh[p][d0 * 128 + ((gk ^ swB0) & 15) * 8];
      half8 b1 =
          *(const half8*)&u_.p3.Xh[p][d1 * 128 + ((gk ^ swB1) & 15) * 8];
      acc0 = __builtin_amdgcn_mfma_f32_16x16x32_f16(af, b0, acc0, 0, 0, 0);
      acc1 = __builtin_amdgcn_mfma_f32_16x16x32_f16(af, b1, acc1, 0, 0, 0);
    }
    if (c < 7) {
      stage_x(p ^ 1, xv);
      stage_T(c + 1, p ^ 1);
    }
    __syncthreads();
  }

  // ---- store: C tile row = o (4*kq+rg), col = d (ml) ----
  #pragma unroll
  for (int rg = 0; rg < 4; ++rg) {
    const int o = 16 * ota + 4 * kq + rg;
    float* op = out + ((size_t)nb * 64 + o) * 512 + m * 128;
    op[d0] = acc0[rg];
    op[d1] = acc1[rg];
  }
}

extern "C" void kernel_launch(void* const* d_in, const int* in_sizes, int n_in,
                              void* d_out, int out_size, void* d_ws, size_t ws_size,
                              hipStream_t stream) {
  const float* x = (const float*)d_in[0];  // [64][1024][128] fp32
  const float* w = (const float*)d_in[1];  // [4][64][128] fp32
  float* out = (float*)d_out;              // [64][64][512] fp32
  ot_fused_kernel<<<256, 1024, 0, stream>>>(x, w, out);
}

// Round 6
// 190.730 us; speedup vs baseline: 1.0310x; 1.0310x over previous
//
#include <hip/hip_runtime.h>
#include <hip/hip_fp16.h>

// Fused Sinkhorn OT. n=64, in_size=1024, in_dim=128, heads=4, out_size=64.
// Single kernel, 256 blocks x 1024 threads (1 block/CU):
//   P1: K-GEMM (fp32 pk-fma, W^T staged LDS) -> K in f32 regs (8x8/thread)
//   P2: multiplicative Sinkhorn, ONE barrier/iter. R12 proved MFMA col-sums
//       work but spilled (afr 32 VGPRs + E2 f32 64 VGPRs > 128 cap ->
//       +21MB/dispatch scratch writes). R13: E lives ONLY in f16:
//       E2h[8][4] packed half2 (32 VGPRs) + E^T fragments afr (32 VGPRs)
//       ~= 110 total, no spill.
//       (A) row sums: v_dot2_f32_f16 (f32 accum) + xor1/2/4 quad-DPP.
//       (B) col partials via MFMA: per wave D = E^T(64x64).u, 8x
//           mfma_f32_16x16x32_f16; A-frags built once after P1 via LDS
//           transpose staging; B = u broadcast (4 cvt_pk + 8 ds_bpermute);
//           lanes ml==0 store D col0 as 4x b128 into cw.
//       (C) cross-wave tree-sum + ballot exit (tol 1e-4, skip it<8) + 8x
//           ds_bpermute ev redistribution, packed to f16 ep. Cap 100.
//       f16-E is a FIXED perturbation (perturbed fixed point; residual -> 0);
//       f16-u noise averages over 1024 rows (~2e-5 < tol).
//   P3: out = T^T x on MFMA f32_16x16x32_f16, R7 structure: double-buffered
//       128-row chunks, T built f16 from E2h*u*v at prologue (hhT), next
//       chunk's x loads issued before the MFMA block.

typedef _Float16 half8 __attribute__((ext_vector_type(8)));
typedef _Float16 h2 __attribute__((ext_vector_type(2)));
typedef float f32x4 __attribute__((ext_vector_type(4)));

__device__ __forceinline__ float2 pkfma(float2 a, float2 b, float2 c) {
  return make_float2(fmaf(a.x, b.x, c.x), fmaf(a.y, b.y, c.y));
}

__device__ __forceinline__ float h2dot(h2 a, h2 b, float acc) {
#if __has_builtin(__builtin_amdgcn_fdot2)
  return __builtin_amdgcn_fdot2(a, b, acc, false);
#else
  return fmaf((float)a[0], (float)b[0], fmaf((float)a[1], (float)b[1], acc));
#endif
}

template <int CTRL>
__device__ __forceinline__ float dpp_add(float v) {
  return v + __int_as_float(__builtin_amdgcn_update_dpp(
                 0, __float_as_int(v), CTRL, 0xf, 0xf, true));
}

// XCD-aware batch map: 4 heads of one nb + 8 nb per XCD (4 MB x-slice = L2).
__device__ __forceinline__ void batch_map(int bb, int& nb, int& m) {
  int k = bb >> 3;
  nb = 8 * (bb & 7) + (k >> 2);
  m = k & 3;
}

__global__ __launch_bounds__(1024, 4) void ot_fused_kernel(
    const float* __restrict__ x, const float* __restrict__ w,
    float* __restrict__ out) {
  int nb, m;
  batch_map(blockIdx.x, nb, m);
  const int t = threadIdx.x;
  const int gi = t >> 3;  // rows 8*gi..8*gi+7
  const int gj = t & 7;   // cols 8*gj..8*gj+7
  const int lane = t & 63;
  const int wvw = t >> 6;   // wave 0..15
  const int qi = lane >> 3; // row-oct within wave (local rows 8*qi..+7)
  const int ml = lane & 15;
  const int kq = lane >> 4;

  __shared__ union {
    float wt[128][68];        // P1 staging
    __half tsc[8 * 64 * 72];  // P2 E^T f16 staging (8 wave-slots, once)
    struct {
      __half Xh[2][128 * 128];  // P3 x chunks, f16, [d][i-local] swizzled
      __half To[2][64 * 128];   // P3 T chunks, f16, [o][i-local] swizzled
    } p3;                       // 96 KB
  } u_;
  __shared__ float cw[2][16][68];  // P2 col partials, parity-buffered

  // ---- P1a: stage W^T ----
  const float* wm = w + (size_t)m * 64 * 128;
  for (int e = t; e < 64 * 128; e += 1024) {
    int j = e >> 7, d = e & 127;
    u_.wt[d][j] = wm[e];
  }
  __syncthreads();

  // ---- P1b: K tile (8x8/thread) in f32 ----
  float2 E2[8][4];
  #pragma unroll
  for (int r = 0; r < 8; ++r)
    #pragma unroll
    for (int c = 0; c < 4; ++c) E2[r][c] = make_float2(0.f, 0.f);

  const float* xrow = x + (size_t)nb * 1024 * 128 + (size_t)gi * 8 * 128;
  for (int d = 0; d < 128; d += 4) {
    float2 wr[4][4];
    #pragma unroll
    for (int dd = 0; dd < 4; ++dd) {
      float4 a0 = *(const float4*)&u_.wt[d + dd][8 * gj];
      float4 a1 = *(const float4*)&u_.wt[d + dd][8 * gj + 4];
      wr[dd][0] = make_float2(a0.x, a0.y);
      wr[dd][1] = make_float2(a0.z, a0.w);
      wr[dd][2] = make_float2(a1.x, a1.y);
      wr[dd][3] = make_float2(a1.z, a1.w);
    }
    #pragma unroll
    for (int r = 0; r < 8; ++r) {
      float4 xv = *(const float4*)&xrow[r * 128 + d];
      float xs[4] = {xv.x, xv.y, xv.z, xv.w};
      #pragma unroll
      for (int dd = 0; dd < 4; ++dd)
        #pragma unroll
        for (int c = 0; c < 4; ++c)
          E2[r][c] = pkfma(make_float2(xs[dd], xs[dd]), wr[dd][c], E2[r][c]);
    }
  }
  // EK = exp(K) -> f16 ONLY (E2 f32 dies here; frees 64 VGPRs for P2)
  h2 E2h[8][4];
  #pragma unroll
  for (int r = 0; r < 8; ++r)
    #pragma unroll
    for (int c = 0; c < 4; ++c) {
      h2 hv;
      hv[0] = (_Float16)__expf(E2[r][c].x);
      hv[1] = (_Float16)__expf(E2[r][c].y);
      E2h[r][c] = hv;
    }
  __syncthreads();

  // ---- P2 pre: build E^T f16 A-fragments (once). Per wave: its 64x64
  //      E-block stored TRANSPOSED in LDS ([colE][rowE], stride 72 halves =
  //      144 B, b128-aligned, 2-way-max banks), then 8x ds_read_b128 -> afr.
  //      Two phases of 8 waves (scratch 8 slots x 9216 B = 72 KB).
  half8 afr[4][2];  // [col-tile 16][K-tile 32]
  #pragma unroll
  for (int ph = 0; ph < 2; ++ph) {
    if ((wvw >> 3) == ph) {
      __half* tb = &u_.tsc[(wvw & 7) * 64 * 72];
      #pragma unroll
      for (int cc = 0; cc < 8; ++cc) {  // local col 8*gj+cc
        const int c = cc >> 1, sel = cc & 1;
        union { h2 a[4]; uint4 q; } pk;
        #pragma unroll
        for (int s = 0; s < 4; ++s) {
          h2 hv;
          hv[0] = E2h[2 * s][c][sel];
          hv[1] = E2h[2 * s + 1][c][sel];
          pk.a[s] = hv;
        }
        *(uint4*)&tb[(8 * gj + cc) * 72 + 8 * qi] = pk.q;
      }
    }
    __syncthreads();
    if ((wvw >> 3) == ph) {
      const __half* tb = &u_.tsc[(wvw & 7) * 64 * 72];
      #pragma unroll
      for (int tt = 0; tt < 4; ++tt)
        #pragma unroll
        for (int kk = 0; kk < 2; ++kk)
          afr[tt][kk] =
              *(const half8*)&tb[(16 * tt + ml) * 72 + 32 * kk + 8 * kq];
    }
    __syncthreads();
  }

  // ---- P2: Sinkhorn, 1 barrier/iter ----
  // Scaling: ur = rcp(sum E*v) (true u / a). Fixed point preserved via
  // v = rcp(a*ss); T = diag(a*ur) E diag(v) applied in P3 prologue.
  float ur[8];
  float evj = 1.0f;    // v for column j==lane
  float evh = 0.0625f; // a*evj, residual scale (off critical path)
  const int bpa = 32 * gj;  // ds_bpermute byte base: source lane 8*gj
  h2 eph[4];  // v for cols 8*gj..+7, packed f16 pairs
  {
    h2 one;
    one[0] = (_Float16)1.0f;
    one[1] = (_Float16)1.0f;
    #pragma unroll
    for (int c = 0; c < 4; ++c) eph[c] = one;
  }
  for (int it = 0; it < 100; ++it) {
    const int pb = it & 1;
    // (A) row sums: f16 dot2 (f32 accum) + xor1/2/4 quad-DPP over gj
    #pragma unroll
    for (int r = 0; r < 8; ++r) {
      float sr = 0.f;
      #pragma unroll
      for (int c = 0; c < 4; ++c) sr = h2dot(E2h[r][c], eph[c], sr);
      sr = dpp_add<0xB1>(sr);
      sr = dpp_add<0x4E>(sr);
      sr = dpp_add<0x141>(sr);
      ur[r] = __builtin_amdgcn_rcpf(sr);
    }
    // (B) col partials via MFMA: D_t = (E^T)_t . u over this wave's 64 rows.
    //     u packed f16 into B col 0: pairs (ur[2p],ur[2p+1]) live at source
    //     lane 8*(4*kk+kq); bpermute pulls them into the B-frag lanes.
    {
      unsigned hu[4];
      #pragma unroll
      for (int p2 = 0; p2 < 4; ++p2) {
        __half2 hh =
            __float22half2_rn(make_float2(ur[2 * p2], ur[2 * p2 + 1]));
        hu[p2] = *(unsigned*)&hh;
      }
      half8 bf[2];
      #pragma unroll
      for (int kk = 0; kk < 2; ++kk) {
        union { unsigned u[4]; half8 h; } bw;
        #pragma unroll
        for (int p2 = 0; p2 < 4; ++p2)
          bw.u[p2] = (unsigned)__builtin_amdgcn_ds_bpermute(
              32 * kq + 128 * kk, (int)hu[p2]);
        bf[kk] = bw.h;
      }
      f32x4 Dv[4];
      #pragma unroll
      for (int tt = 0; tt < 4; ++tt) {
        Dv[tt] = f32x4{0.f, 0.f, 0.f, 0.f};
        Dv[tt] = __builtin_amdgcn_mfma_f32_16x16x32_f16(afr[tt][0], bf[0],
                                                        Dv[tt], 0, 0, 0);
        Dv[tt] = __builtin_amdgcn_mfma_f32_16x16x32_f16(afr[tt][1], bf[1],
                                                        Dv[tt], 0, 0, 0);
      }
      // D col 0 (== every col; B cols identical): rows = colE 16*tt+4*kq+reg.
      if (ml == 0) {
        #pragma unroll
        for (int tt = 0; tt < 4; ++tt)
          *(f32x4*)&cw[pb][wvw][16 * tt + 4 * kq] = Dv[tt];
      }
    }
    __syncthreads();
    // (C) every wave: tree-sum 16 partials for col=lane (identical data in
    //     all waves -> exit decision stays wave-uniform), ballot (skipped
    //     for it<8: residual provably >> tol there), redistribute via 8x
    //     ds_bpermute, pack to f16 for (A).
    float sv[16];
    #pragma unroll
    for (int p = 0; p < 16; ++p) sv[p] = cw[pb][p][lane];
    #pragma unroll
    for (int st = 8; st >= 1; st >>= 1)
      #pragma unroll
      for (int p = 0; p < st; ++p) sv[p] += sv[p + st];
    const float ss = sv[0];
    unsigned long long bad = ~0ULL;
    if (it >= 8) bad = __ballot(fabsf(fmaf(ss, evh, -1.0f)) > 1e-4f);
    evj = __builtin_amdgcn_rcpf(ss * 0.0625f);
    evh = 0.0625f * evj;
    int e[8];
    #pragma unroll
    for (int k = 0; k < 8; ++k)
      e[k] = __builtin_amdgcn_ds_bpermute(bpa + 4 * k, __float_as_int(evj));
    #pragma unroll
    for (int c = 0; c < 4; ++c) {
      h2 hv;
      hv[0] = (_Float16)__int_as_float(e[2 * c]);
      hv[1] = (_Float16)__int_as_float(e[2 * c + 1]);
      eph[c] = hv;
    }
    if (bad == 0ULL) break;
  }

  // ---- P3 prologue: T = (a*ur)*E*v built straight into f16 regs hhT ----
  float usr[8];
  #pragma unroll
  for (int r = 0; r < 8; ++r) usr[r] = ur[r] * 0.0625f;
  __half2 hhT[8][4];  // hhT[co][q] = (T[2q][co], T[2q+1][co])
  #pragma unroll
  for (int co = 0; co < 8; ++co) {
    const int c = co >> 1, sel = co & 1;
    const float vc = (float)eph[c][sel];
    #pragma unroll
    for (int q = 0; q < 4; ++q) {
      float va = (float)E2h[2 * q][c][sel] * usr[2 * q] * vc;
      float vb = (float)E2h[2 * q + 1][c][sel] * usr[2 * q + 1] * vc;
      hhT[co][q] = __float22half2_rn(make_float2(va, vb));
    }
  }

  // ---- P3: out = T^T x via MFMA, double-buffered 128-row chunks ----
  const int ig4 = t >> 5;    // i-quad group 0..31 (rows 4*ig4..+3 of chunk)
  const int dq = t & 31;     // d-quad
  const int o8w = ig4 >> 1;  // logical i-oct of this stager
  const int hw = ig4 & 1;    // half within oct
  const int ota = wvw & 3;
  const int dtb = wvw >> 2;
  const int oA = 16 * ota + ml;
  const int d0 = 32 * dtb + ml;
  const int d1 = d0 + 16;
  const int swA = oA & 15;
  const int swB0 = ((d0 >> 2) & 15) ^ ((d0 & 3) << 2);
  const int swB1 = ((d1 >> 2) & 15) ^ ((d1 & 3) << 2);

  f32x4 acc0 = {0.f, 0.f, 0.f, 0.f}, acc1 = {0.f, 0.f, 0.f, 0.f};
  const float* xb = x + (size_t)nb * 1024 * 128;

  auto stage_x = [&](int p, const float4* xv) {
    #pragma unroll
    for (int k = 0; k < 4; ++k) {
      const float* f0 = (const float*)&xv[0];
      const float* f1 = (const float*)&xv[1];
      const float* f2 = (const float*)&xv[2];
      const float* f3 = (const float*)&xv[3];
      __half2 hp[2];
      hp[0] = __float22half2_rn(make_float2(f0[k], f1[k]));
      hp[1] = __float22half2_rn(make_float2(f2[k], f3[k]));
      const int d = 4 * dq + k;
      const int pos = (o8w ^ (dq & 15) ^ (k << 2)) & 15;
      *(uint2*)&u_.p3.Xh[p][d * 128 + pos * 8 + hw * 4] = *(uint2*)hp;
    }
  };
  auto stage_T = [&](int c, int p) {
    if ((t >> 7) == c) {  // this thread's 8 rows live in chunk c
      const int g = gi & 15;
      #pragma unroll
      for (int co = 0; co < 8; ++co) {
        const int o = 8 * gj + co;
        const int pos = (g ^ (o & 15)) & 15;
        *(uint4*)&u_.p3.To[p][o * 128 + pos * 8] = *(const uint4*)&hhT[co][0];
      }
    }
  };

  // prologue: stage chunk 0 into buf 0
  {
    float4 xv[4];
    const float* xs = xb + (size_t)(4 * ig4) * 128 + 4 * dq;
    #pragma unroll
    for (int r = 0; r < 4; ++r) xv[r] = *(const float4*)(xs + r * 128);
    stage_x(0, xv);
    stage_T(0, 0);
  }
  __syncthreads();

  for (int c = 0; c < 8; ++c) {
    const int p = c & 1;
    float4 xv[4];
    if (c < 7) {  // issue next chunk's loads; complete under MFMA below
      const float* xs = xb + (size_t)(128 * (c + 1) + 4 * ig4) * 128 + 4 * dq;
      #pragma unroll
      for (int r = 0; r < 4; ++r) xv[r] = *(const float4*)(xs + r * 128);
    }
    // MFMA on current buffer: 4 K-steps of 32
    #pragma unroll
    for (int s = 0; s < 4; ++s) {
      const int gk = 4 * s + kq;
      half8 af =
          *(const half8*)&u_.p3.To[p][oA * 128 + ((gk ^ swA) & 15) * 8];
      half8 b0 =
          *(const half8*)&u_.p3.Xh[p][d0 * 128 + ((gk ^ swB0) & 15) * 8];
      half8 b1 =
          *(const half8*)&u_.p3.Xh[p][d1 * 128 + ((gk ^ swB1) & 15) * 8];
      acc0 = __builtin_amdgcn_mfma_f32_16x16x32_f16(af, b0, acc0, 0, 0, 0);
      acc1 = __builtin_amdgcn_mfma_f32_16x16x32_f16(af, b1, acc1, 0, 0, 0);
    }
    if (c < 7) {
      stage_x(p ^ 1, xv);
      stage_T(c + 1, p ^ 1);
    }
    __syncthreads();
  }

  // ---- store: C tile row = o (4*kq+rg), col = d (ml) ----
  #pragma unroll
  for (int rg = 0; rg < 4; ++rg) {
    const int o = 16 * ota + 4 * kq + rg;
    float* op = out + ((size_t)nb * 64 + o) * 512 + m * 128;
    op[d0] = acc0[rg];
    op[d1] = acc1[rg];
  }
}

extern "C" void kernel_launch(void* const* d_in, const int* in_sizes, int n_in,
                              void* d_out, int out_size, void* d_ws, size_t ws_size,
                              hipStream_t stream) {
  const float* x = (const float*)d_in[0];  // [64][1024][128] fp32
  const float* w = (const float*)d_in[1];  // [4][64][128] fp32
  float* out = (float*)d_out;              // [64][64][512] fp32
  ot_fused_kernel<<<256, 1024, 0, stream>>>(x, w, out);
}

// Round 7
// 183.865 us; speedup vs baseline: 1.0695x; 1.0373x over previous
//
#include <hip/hip_runtime.h>
#include <hip/hip_fp16.h>

// Fused Sinkhorn OT. n=64, in_size=1024, in_dim=128, heads=4, out_size=64.
// Single kernel, 256 blocks x 1024 threads (1 block/CU):
//   P1: K-GEMM (fp32 pk-fma, W^T staged LDS) -> K f32, then EK=exp(K) stored
//       ONLY as f16 pairs E2h (32 VGPRs; R13-proven precision).
//   P2: multiplicative Sinkhorn. R14 model: P2 was DS-PIPE-bound (~420-580
//       DS instrs/CU/iter on the shared LDS pipe; 16 waves duplicated the
//       same (C) reduction). Redesign: SINGLE-REDUCER wave + 2 barriers/iter,
//       82 DS instrs/CU/iter (5x cut), everything else VALU:
//       (A) row sums: v_dot2_f32_f16 + xor1/2/4 quad-DPP (all waves).
//       (B) col partials: v_fma_mix (f16 E x f32 u, f32 acc) + R8-proven
//           xor8 DPP / xor16,xor32 permlane butterfly (all waves); lanes<8
//           write 2x b128 partials to cw (single-buffered).
//       B1. Wave 0 ONLY: 16x b32 tree-sum, residual ballot (skip it<8,
//           tol 1e-4), ev update, pack ev->f16 pairs, 1x b32 write + flag.
//       B2. All waves: 1x b128 ep read + 1x b32 flag (broadcast); uniform
//           break. Barriers separate all write/read pairs (no parity bufs).
//       No MFMA in P2 (R12/13 lesson: afr regs spilled; VALU had headroom).
//       Live regs ~70 -> no spill. Cap 100.
//   P3: out = T^T x on MFMA f32_16x16x32_f16, R7 structure: double-buffered
//       128-row chunks, T built f16 from E2h*u*v at prologue (hhT), next
//       chunk's x loads issued before the MFMA block.
// __launch_bounds__(1024) (no min-waves arg): workgroup residency caps VGPR
// at 128; don't pin the allocator below that.

typedef _Float16 half8 __attribute__((ext_vector_type(8)));
typedef _Float16 h2 __attribute__((ext_vector_type(2)));
typedef float f32x4 __attribute__((ext_vector_type(4)));
typedef unsigned uint2v __attribute__((ext_vector_type(2)));

__device__ __forceinline__ float2 pkfma(float2 a, float2 b, float2 c) {
  return make_float2(fmaf(a.x, b.x, c.x), fmaf(a.y, b.y, c.y));
}

__device__ __forceinline__ float h2dot(h2 a, h2 b, float acc) {
#if __has_builtin(__builtin_amdgcn_fdot2)
  return __builtin_amdgcn_fdot2(a, b, acc, false);
#else
  return fmaf((float)a[0], (float)b[0], fmaf((float)a[1], (float)b[1], acc));
#endif
}

template <int CTRL>
__device__ __forceinline__ float dpp_add(float v) {
  return v + __int_as_float(__builtin_amdgcn_update_dpp(
                 0, __float_as_int(v), CTRL, 0xf, 0xf, true));
}

template <int CTRL>
__device__ __forceinline__ float dpp_mov(float v) {
  return __int_as_float(__builtin_amdgcn_update_dpp(
      0, __float_as_int(v), CTRL, 0xf, 0xf, true));
}

// xor16 / xor32 butterfly adds. VALU-pipe permlane swaps on gfx950;
// DS-pipe fallbacks otherwise.
#if __has_builtin(__builtin_amdgcn_permlane16_swap)
__device__ __forceinline__ float x16_add(float v) {
  uint2v r = __builtin_amdgcn_permlane16_swap(__float_as_uint(v),
                                              __float_as_uint(v), false,
                                              false);
  return __uint_as_float(r.x) + __uint_as_float(r.y);
}
#else
__device__ __forceinline__ float x16_add(float v) {
  return v + __int_as_float(
                 __builtin_amdgcn_ds_swizzle(__float_as_int(v), 0x401F));
}
#endif
#if __has_builtin(__builtin_amdgcn_permlane32_swap)
__device__ __forceinline__ float x32_add(float v) {
  uint2v r = __builtin_amdgcn_permlane32_swap(__float_as_uint(v),
                                              __float_as_uint(v), false,
                                              false);
  return __uint_as_float(r.x) + __uint_as_float(r.y);
}
#else
__device__ __forceinline__ float x32_add(float v) {
  return v + __shfl_xor(v, 32, 64);
}
#endif

// XCD-aware batch map: 4 heads of one nb + 8 nb per XCD (4 MB x-slice = L2).
__device__ __forceinline__ void batch_map(int bb, int& nb, int& m) {
  int k = bb >> 3;
  nb = 8 * (bb & 7) + (k >> 2);
  m = k & 3;
}

__global__ __launch_bounds__(1024) void ot_fused_kernel(
    const float* __restrict__ x, const float* __restrict__ w,
    float* __restrict__ out) {
  int nb, m;
  batch_map(blockIdx.x, nb, m);
  const int t = threadIdx.x;
  const int gi = t >> 3;  // rows 8*gi..8*gi+7
  const int gj = t & 7;   // cols 8*gj..8*gj+7
  const int lane = t & 63;
  const int wvw = t >> 6;  // wave 0..15
  const int ml = lane & 15;
  const int kq = lane >> 4;

  __shared__ union {
    float wt[128][68];  // P1 staging
    struct {
      __half Xh[2][128 * 128];  // P3 x chunks, f16, [d][i-local] swizzled
      __half To[2][64 * 128];   // P3 T chunks, f16, [o][i-local] swizzled
    } p3;                       // 96 KB
  } u_;
  __shared__ float cw[16][68];  // P2 col partials (single buffer, 2 barriers)
  __shared__ __align__(16) unsigned evb[36];  // ev f16 pairs [0..31] + flag[32]

  // ---- P1a: stage W^T ----
  const float* wm = w + (size_t)m * 64 * 128;
  for (int e = t; e < 64 * 128; e += 1024) {
    int j = e >> 7, d = e & 127;
    u_.wt[d][j] = wm[e];
  }
  __syncthreads();

  // ---- P1b: K tile (8x8/thread) in f32 ----
  float2 E2[8][4];
  #pragma unroll
  for (int r = 0; r < 8; ++r)
    #pragma unroll
    for (int c = 0; c < 4; ++c) E2[r][c] = make_float2(0.f, 0.f);

  const float* xrow = x + (size_t)nb * 1024 * 128 + (size_t)gi * 8 * 128;
  for (int d = 0; d < 128; d += 4) {
    float2 wr[4][4];
    #pragma unroll
    for (int dd = 0; dd < 4; ++dd) {
      float4 a0 = *(const float4*)&u_.wt[d + dd][8 * gj];
      float4 a1 = *(const float4*)&u_.wt[d + dd][8 * gj + 4];
      wr[dd][0] = make_float2(a0.x, a0.y);
      wr[dd][1] = make_float2(a0.z, a0.w);
      wr[dd][2] = make_float2(a1.x, a1.y);
      wr[dd][3] = make_float2(a1.z, a1.w);
    }
    #pragma unroll
    for (int r = 0; r < 8; ++r) {
      float4 xv = *(const float4*)&xrow[r * 128 + d];
      float xs[4] = {xv.x, xv.y, xv.z, xv.w};
      #pragma unroll
      for (int dd = 0; dd < 4; ++dd)
        #pragma unroll
        for (int c = 0; c < 4; ++c)
          E2[r][c] = pkfma(make_float2(xs[dd], xs[dd]), wr[dd][c], E2[r][c]);
    }
  }
  // EK = exp(K) -> f16 ONLY (E2 f32 dies here)
  h2 E2h[8][4];
  #pragma unroll
  for (int r = 0; r < 8; ++r)
    #pragma unroll
    for (int c = 0; c < 4; ++c) {
      h2 hv;
      hv[0] = (_Float16)__expf(E2[r][c].x);
      hv[1] = (_Float16)__expf(E2[r][c].y);
      E2h[r][c] = hv;
    }
  __syncthreads();

  // ---- P2: Sinkhorn, single-reducer, 2 barriers/iter ----
  // Scaling: ur = rcp(sum E*v) (true u / a); v = rcp(a*ss);
  // T = diag(a*ur) E diag(v) applied in P3 prologue.
  float ur[8];
  float evj = 1.0f;     // wave-0 state: v for col==lane
  float evh = 0.0625f;  // wave-0 state: a*v, residual scale
  h2 eph[4];            // v for cols 8*gj..+7, f16 pairs (all waves)
  {
    h2 one;
    one[0] = (_Float16)1.0f;
    one[1] = (_Float16)1.0f;
    #pragma unroll
    for (int c = 0; c < 4; ++c) eph[c] = one;
  }
  for (int it = 0; it < 100; ++it) {
    // (A) row sums: f16 dot2 (f32 accum) + xor1/2/4 quad-DPP over gj
    #pragma unroll
    for (int r = 0; r < 8; ++r) {
      float sr = 0.f;
      #pragma unroll
      for (int c = 0; c < 4; ++c) sr = h2dot(E2h[r][c], eph[c], sr);
      sr = dpp_add<0xB1>(sr);
      sr = dpp_add<0x4E>(sr);
      sr = dpp_add<0x141>(sr);
      ur[r] = __builtin_amdgcn_rcpf(sr);
    }
    // (B) col partials: fma_mix over own 8 rows, then xor8 (DPP) +
    //     xor16/xor32 (permlane) -> full wave col-sum at every lane
    float ca[8];
    #pragma unroll
    for (int k = 0; k < 8; ++k) ca[k] = 0.f;
    #pragma unroll
    for (int r = 0; r < 8; ++r)
      #pragma unroll
      for (int k = 0; k < 8; ++k)
        ca[k] = fmaf((float)E2h[r][k >> 1][k & 1], ur[r], ca[k]);
    #pragma unroll
    for (int k = 0; k < 8; ++k) {
      ca[k] = dpp_add<0x128>(ca[k]);  // xor8 within 16 (row_ror:8)
      ca[k] = x16_add(ca[k]);         // xor16 (VALU permlane swap)
      ca[k] = x32_add(ca[k]);         // xor32 (VALU permlane swap)
    }
    if (lane < 8) {  // lane==gj covers all 64 cols
      *(float4*)&cw[wvw][8 * lane] = make_float4(ca[0], ca[1], ca[2], ca[3]);
      *(float4*)&cw[wvw][8 * lane + 4] =
          make_float4(ca[4], ca[5], ca[6], ca[7]);
    }
    __syncthreads();  // B1: partials visible
    // Wave 0 only: cross-wave reduce col=lane, residual, ev update, publish
    if (wvw == 0) {
      float sv[16];
      #pragma unroll
      for (int p = 0; p < 16; ++p) sv[p] = cw[p][lane];
      #pragma unroll
      for (int st = 8; st >= 1; st >>= 1)
        #pragma unroll
        for (int p = 0; p < st; ++p) sv[p] += sv[p + st];
      const float ss = sv[0];
      int flagv = 1;
      if (it >= 8) {
        unsigned long long bad =
            __ballot(fabsf(fmaf(ss, evh, -1.0f)) > 1e-4f);
        flagv = (bad == 0ULL) ? 0 : 1;
      }
      evj = __builtin_amdgcn_rcpf(ss * 0.0625f);
      evh = 0.0625f * evj;
      const float evn = dpp_mov<0xB1>(evj);  // neighbor col's ev (xor1)
      if (!(lane & 1)) {
        h2 hv;
        hv[0] = (_Float16)evj;
        hv[1] = (_Float16)evn;
        union { h2 h; unsigned u; } cc;
        cc.h = hv;
        evb[lane >> 1] = cc.u;
      }
      if (lane == 0) evb[32] = (unsigned)flagv;
    }
    __syncthreads();  // B2: ev + flag visible
    const uint4 ew = *(const uint4*)&evb[4 * gj];
    const unsigned fl = evb[32];
    union { unsigned u; h2 h; } c0, c1, c2, c3;
    c0.u = ew.x; c1.u = ew.y; c2.u = ew.z; c3.u = ew.w;
    eph[0] = c0.h; eph[1] = c1.h; eph[2] = c2.h; eph[3] = c3.h;
    if (fl == 0u) break;
  }

  // ---- P3 prologue: T = (a*ur)*E*v built straight into f16 regs hhT ----
  float usr[8];
  #pragma unroll
  for (int r = 0; r < 8; ++r) usr[r] = ur[r] * 0.0625f;
  __half2 hhT[8][4];  // hhT[co][q] = (T[2q][co], T[2q+1][co])
  #pragma unroll
  for (int co = 0; co < 8; ++co) {
    const int c = co >> 1, sel = co & 1;
    const float vc = (float)eph[c][sel];
    #pragma unroll
    for (int q = 0; q < 4; ++q) {
      float va = (float)E2h[2 * q][c][sel] * usr[2 * q] * vc;
      float vb = (float)E2h[2 * q + 1][c][sel] * usr[2 * q + 1] * vc;
      hhT[co][q] = __float22half2_rn(make_float2(va, vb));
    }
  }

  // ---- P3: out = T^T x via MFMA, double-buffered 128-row chunks ----
  const int ig4 = t >> 5;    // i-quad group 0..31 (rows 4*ig4..+3 of chunk)
  const int dq = t & 31;     // d-quad
  const int o8w = ig4 >> 1;  // logical i-oct of this stager
  const int hw = ig4 & 1;    // half within oct
  const int ota = wvw & 3;
  const int dtb = wvw >> 2;
  const int oA = 16 * ota + ml;
  const int d0 = 32 * dtb + ml;
  const int d1 = d0 + 16;
  const int swA = oA & 15;
  const int swB0 = ((d0 >> 2) & 15) ^ ((d0 & 3) << 2);
  const int swB1 = ((d1 >> 2) & 15) ^ ((d1 & 3) << 2);

  f32x4 acc0 = {0.f, 0.f, 0.f, 0.f}, acc1 = {0.f, 0.f, 0.f, 0.f};
  const float* xb = x + (size_t)nb * 1024 * 128;

  auto stage_x = [&](int p, const float4* xv) {
    #pragma unroll
    for (int k = 0; k < 4; ++k) {
      const float* f0 = (const float*)&xv[0];
      const float* f1 = (const float*)&xv[1];
      const float* f2 = (const float*)&xv[2];
      const float* f3 = (const float*)&xv[3];
      __half2 hp[2];
      hp[0] = __float22half2_rn(make_float2(f0[k], f1[k]));
      hp[1] = __float22half2_rn(make_float2(f2[k], f3[k]));
      const int d = 4 * dq + k;
      const int pos = (o8w ^ (dq & 15) ^ (k << 2)) & 15;
      *(uint2*)&u_.p3.Xh[p][d * 128 + pos * 8 + hw * 4] = *(uint2*)hp;
    }
  };
  auto stage_T = [&](int c, int p) {
    if ((t >> 7) == c) {  // this thread's 8 rows live in chunk c
      const int g = gi & 15;
      #pragma unroll
      for (int co = 0; co < 8; ++co) {
        const int o = 8 * gj + co;
        const int pos = (g ^ (o & 15)) & 15;
        *(uint4*)&u_.p3.To[p][o * 128 + pos * 8] = *(const uint4*)&hhT[co][0];
      }
    }
  };

  // prologue: stage chunk 0 into buf 0
  {
    float4 xv[4];
    const float* xs = xb + (size_t)(4 * ig4) * 128 + 4 * dq;
    #pragma unroll
    for (int r = 0; r < 4; ++r) xv[r] = *(const float4*)(xs + r * 128);
    stage_x(0, xv);
    stage_T(0, 0);
  }
  __syncthreads();

  for (int c = 0; c < 8; ++c) {
    const int p = c & 1;
    float4 xv[4];
    if (c < 7) {  // issue next chunk's loads; complete under MFMA below
      const float* xs = xb + (size_t)(128 * (c + 1) + 4 * ig4) * 128 + 4 * dq;
      #pragma unroll
      for (int r = 0; r < 4; ++r) xv[r] = *(const float4*)(xs + r * 128);
    }
    // MFMA on current buffer: 4 K-steps of 32
    #pragma unroll
    for (int s = 0; s < 4; ++s) {
      const int gk = 4 * s + kq;
      half8 af =
          *(const half8*)&u_.p3.To[p][oA * 128 + ((gk ^ swA) & 15) * 8];
      half8 b0 =
          *(const half8*)&u_.p3.Xh[p][d0 * 128 + ((gk ^ swB0) & 15) * 8];
      half8 b1 =
          *(const half8*)&u_.p3.Xh[p][d1 * 128 + ((gk ^ swB1) & 15) * 8];
      acc0 = __builtin_amdgcn_mfma_f32_16x16x32_f16(af, b0, acc0, 0, 0, 0);
      acc1 = __builtin_amdgcn_mfma_f32_16x16x32_f16(af, b1, acc1, 0, 0, 0);
    }
    if (c < 7) {
      stage_x(p ^ 1, xv);
      stage_T(c + 1, p ^ 1);
    }
    __syncthreads();
  }

  // ---- store: C tile row = o (4*kq+rg), col = d (ml) ----
  #pragma unroll
  for (int rg = 0; rg < 4; ++rg) {
    const int o = 16 * ota + 4 * kq + rg;
    float* op = out + ((size_t)nb * 64 + o) * 512 + m * 128;
    op[d0] = acc0[rg];
    op[d1] = acc1[rg];
  }
}

extern "C" void kernel_launch(void* const* d_in, const int* in_sizes, int n_in,
                              void* d_out, int out_size, void* d_ws, size_t ws_size,
                              hipStream_t stream) {
  const float* x = (const float*)d_in[0];  // [64][1024][128] fp32
  const float* w = (const float*)d_in[1];  // [4][64][128] fp32
  float* out = (float*)d_out;              // [64][64][512] fp32
  ot_fused_kernel<<<256, 1024, 0, stream>>>(x, w, out);
}